// Round 1
// baseline (964.574 us; speedup 1.0000x reference)
//
#include <hip/hip_runtime.h>

// Problem constants (B=512, C=640, S=14, T=196, H=32)
constexpr int kB = 512;
constexpr int kC = 640;
constexpr int kT = 196;   // tokens
constexpr int kTP = 224;  // tokens padded to 7*32
constexpr int kH = 32;    // MLP hidden
constexpr int kKSTEP = 32; // K staged per iteration (2 MFMA k-steps)

typedef __bf16 bf16x8 __attribute__((ext_vector_type(8)));
typedef float  f32x16 __attribute__((ext_vector_type(16)));

__device__ __forceinline__ unsigned f2bfbits(float x) {
  // round-to-nearest-even fp32 -> bf16 bits
  unsigned u = __builtin_bit_cast(unsigned, x);
  return (u + 0x7FFFu + ((u >> 16) & 1u)) >> 16;
}
__device__ __forceinline__ float bf2f(unsigned short v) {
  return __builtin_bit_cast(float, (unsigned)v << 16);
}

// ---------------------------------------------------------------------------
// Kernel 1: per-batch corr = l2norm(class_tok) @ l2norm(query_tok)^T, bf16 out.
// Tokens are columns of feat[b] ([C][T] layout). We compute the raw bf16 dot
// with MFMA and apply inv-norms (fp32 sum-of-squares, fused into staging) in
// the epilogue. M=N padded 196->224 (7 32-tiles), K=640 (20 stages of 32).
// LDS layout: P[k2][t] u32 packing bf16 pair (k=2*k2 lo, 2*k2+1 hi):
//   staging writes are contiguous ds_write_b128 (conflict-free),
//   fragment reads are 4x ds_read_b32, lanes contiguous (conflict-free).
// ---------------------------------------------------------------------------
__global__ __launch_bounds__(448) void corr_kernel(
    const float* __restrict__ cf, const float* __restrict__ qf,
    unsigned short* __restrict__ corr_out)
{
  __shared__ int Al[(kKSTEP/2) * kTP];   // 16*224 u32 = 14336 B
  __shared__ int Bl[(kKSTEP/2) * kTP];
  __shared__ float ssA[kTP], ssB[kTP], invA[kTP], invB[kTP];

  const int b    = blockIdx.x;
  const int tid  = threadIdx.x;
  const int wave = tid >> 6;        // 0..6 : M strip = rows [32w, 32w+32)
  const int lane = tid & 63;
  const int hf   = lane >> 5;       // half-wave
  const int l31  = lane & 31;

  const float4* Ap = (const float4*)(cf + (size_t)b * kC * kT); // row = 49 float4
  const float4* Bp = (const float4*)(qf + (size_t)b * kC * kT);

  const int t4 = tid % 56;          // float4 column (49 real + 7 pad)
  const int kr = tid / 56;          // 0..7
  const bool realcol = (t4 < 49);

  if (tid < kTP) { ssA[tid] = 0.f; ssB[tid] = 0.f; }

  float4 sa = {0.f,0.f,0.f,0.f}, sb = {0.f,0.f,0.f,0.f};

  f32x16 acc[7];
#pragma unroll
  for (int c = 0; c < 7; ++c)
#pragma unroll
    for (int r = 0; r < 16; ++r) acc[c][r] = 0.f;

  const int mrow = 32 * wave + l31;

  for (int s = 0; s < kC / kKSTEP; ++s) {
    const int k0 = s * kKSTEP;
    __syncthreads();  // previous stage's fragment reads done
#pragma unroll
    for (int i = 0; i < 2; ++i) {
      const int k2 = kr + 8 * i;                 // u32 row, covers k = 2k2, 2k2+1
      float4 a0 = {0,0,0,0}, a1 = {0,0,0,0}, b0 = {0,0,0,0}, b1 = {0,0,0,0};
      if (realcol) {
        const size_t r0 = (size_t)(k0 + 2 * k2) * 49 + t4;
        a0 = Ap[r0]; a1 = Ap[r0 + 49];
        b0 = Bp[r0]; b1 = Bp[r0 + 49];
      }
      sa.x += a0.x*a0.x + a1.x*a1.x;  sa.y += a0.y*a0.y + a1.y*a1.y;
      sa.z += a0.z*a0.z + a1.z*a1.z;  sa.w += a0.w*a0.w + a1.w*a1.w;
      sb.x += b0.x*b0.x + b1.x*b1.x;  sb.y += b0.y*b0.y + b1.y*b1.y;
      sb.z += b0.z*b0.z + b1.z*b1.z;  sb.w += b0.w*b0.w + b1.w*b1.w;
      uint4 aw, bw;
      aw.x = f2bfbits(a0.x) | (f2bfbits(a1.x) << 16);
      aw.y = f2bfbits(a0.y) | (f2bfbits(a1.y) << 16);
      aw.z = f2bfbits(a0.z) | (f2bfbits(a1.z) << 16);
      aw.w = f2bfbits(a0.w) | (f2bfbits(a1.w) << 16);
      bw.x = f2bfbits(b0.x) | (f2bfbits(b1.x) << 16);
      bw.y = f2bfbits(b0.y) | (f2bfbits(b1.y) << 16);
      bw.z = f2bfbits(b0.z) | (f2bfbits(b1.z) << 16);
      bw.w = f2bfbits(b0.w) | (f2bfbits(b1.w) << 16);
      ((uint4*)Al)[k2 * 56 + t4] = aw;           // contiguous across lanes
      ((uint4*)Bl)[k2 * 56 + t4] = bw;
    }
    __syncthreads();
#pragma unroll
    for (int kk = 0; kk < 2; ++kk) {
      const int base = (kk * 8 + hf * 4) * kTP;  // u32 row base for this frag
      int4 av;
      av.x = Al[base          + mrow];
      av.y = Al[base + kTP    + mrow];
      av.z = Al[base + 2*kTP  + mrow];
      av.w = Al[base + 3*kTP  + mrow];
      bf16x8 af = __builtin_bit_cast(bf16x8, av);
#pragma unroll
      for (int c = 0; c < 7; ++c) {
        const int nrow = 32 * c + l31;
        int4 bv;
        bv.x = Bl[base          + nrow];
        bv.y = Bl[base + kTP    + nrow];
        bv.z = Bl[base + 2*kTP  + nrow];
        bv.w = Bl[base + 3*kTP  + nrow];
        bf16x8 bfv = __builtin_bit_cast(bf16x8, bv);
        acc[c] = __builtin_amdgcn_mfma_f32_32x32x16_bf16(af, bfv, acc[c], 0, 0, 0);
      }
    }
  }

  // reduce per-column sum of squares (each thread owns cols 4*t4..4*t4+3,
  // rows k2 ≡ kr (mod 8); 8 kr-cohorts cover all k)
  if (realcol) {
    atomicAdd(&ssA[4*t4+0], sa.x); atomicAdd(&ssA[4*t4+1], sa.y);
    atomicAdd(&ssA[4*t4+2], sa.z); atomicAdd(&ssA[4*t4+3], sa.w);
    atomicAdd(&ssB[4*t4+0], sb.x); atomicAdd(&ssB[4*t4+1], sb.y);
    atomicAdd(&ssB[4*t4+2], sb.z); atomicAdd(&ssB[4*t4+3], sb.w);
  }
  __syncthreads();
  if (tid < kTP) {
    invA[tid] = 1.0f / fmaxf(sqrtf(ssA[tid]), 1e-12f);
    invB[tid] = 1.0f / fmaxf(sqrtf(ssB[tid]), 1e-12f);
  }
  __syncthreads();

  // epilogue: corr[t][u] = raw * invA[t] * invB[u], store bf16
  unsigned short* co = corr_out + (size_t)b * kT * kT;
#pragma unroll
  for (int c = 0; c < 7; ++c) {
    const int u = 32 * c + l31;
    if (u < kT) {
      const float ivu = invB[u];
#pragma unroll
      for (int r = 0; r < 16; ++r) {
        const int t = 32 * wave + (r & 3) + 8 * (r >> 2) + 4 * hf;
        if (t < kT) {
          co[t * kT + u] = (unsigned short)f2bfbits(acc[c][r] * invA[t] * ivu);
        }
      }
    }
  }
}

// ---------------------------------------------------------------------------
// Kernel 2: per-batch attention weights. Stage corr[b] (77 KB bf16) in LDS,
// compute col/row means, both MLPs, logits (/0.025), softmax -> attn_c/attn_q.
// ---------------------------------------------------------------------------
__device__ __forceinline__ void softmax196(float lgv, int tid, float* red, float* outp) {
  red[tid] = lgv;
  __syncthreads();
  for (int o = 128; o > 0; o >>= 1) {
    if (tid < o) red[tid] = fmaxf(red[tid], red[tid + o]);
    __syncthreads();
  }
  const float mx = red[0];
  __syncthreads();
  const float e = (tid < kT) ? __expf(lgv - mx) : 0.f;
  red[tid] = e;
  __syncthreads();
  for (int o = 128; o > 0; o >>= 1) {
    if (tid < o) red[tid] += red[tid + o];
    __syncthreads();
  }
  const float inv = 1.0f / red[0];
  if (tid < kT) outp[tid] = e * inv;
  __syncthreads();
}

__global__ __launch_bounds__(256) void attn_kernel(
    const unsigned short* __restrict__ corr,
    const float* __restrict__ w1c, const float* __restrict__ b1c,
    const float* __restrict__ w2c, const float* __restrict__ b2c,
    const float* __restrict__ w1q, const float* __restrict__ b1q,
    const float* __restrict__ w2q, const float* __restrict__ b2q,
    float* __restrict__ attnC, float* __restrict__ attnQ)
{
  __shared__ __align__(16) unsigned short cs[kT * kT];  // 76832 B
  __shared__ float mC[kT], mQ[kT], hid[kH], kern[kT], red[256];

  const int b = blockIdx.x, tid = threadIdx.x;
  // stage corr[b] into LDS (4802 uint4 exactly)
  {
    const uint4* src = (const uint4*)(corr + (size_t)b * kT * kT);
    uint4* dst = (uint4*)cs;
    for (int i = tid; i < kT * kT / 8; i += 256) dst[i] = src[i];
  }
  __syncthreads();

  if (tid < kT) {
    float s = 0.f, s2 = 0.f;
    for (int t = 0; t < kT; ++t) s  += bf2f(cs[t * kT + tid]); // col scan: conflict-free
    for (int u = 0; u < kT; ++u) s2 += bf2f(cs[tid * kT + u]); // row scan
    mC[tid] = s  * (1.0f / kT);   // mean over t  -> class MLP input
    mQ[tid] = s2 * (1.0f / kT);   // mean over u  -> query MLP input
  }
  __syncthreads();

  // ---- class path ----
  if (tid < kH) {
    float s = b1c[tid];
    for (int u = 0; u < kT; ++u) s += mC[u] * w1c[u * kH + tid];
    hid[tid] = fmaxf(s, 0.f);
  }
  __syncthreads();
  if (tid < kT) {
    float s = b2c[tid];
    for (int h = 0; h < kH; ++h) s += hid[h] * w2c[h * kT + tid];
    kern[tid] = s;
  }
  __syncthreads();
  float lgv = -3.4e38f;
  if (tid < kT) {
    float s = 0.f;
    for (int u = 0; u < kT; ++u) s += bf2f(cs[tid * kT + u]) * kern[u];
    lgv = s * 40.0f;  // / TEMPERATURE (0.025)
  }
  softmax196(lgv, tid, red, attnC + (size_t)b * kT);

  // ---- query path (corr^T) ----
  if (tid < kH) {
    float s = b1q[tid];
    for (int u = 0; u < kT; ++u) s += mQ[u] * w1q[u * kH + tid];
    hid[tid] = fmaxf(s, 0.f);
  }
  __syncthreads();
  if (tid < kT) {
    float s = b2q[tid];
    for (int h = 0; h < kH; ++h) s += hid[h] * w2q[h * kT + tid];
    kern[tid] = s;
  }
  __syncthreads();
  lgv = -3.4e38f;
  if (tid < kT) {
    float s = 0.f;
    for (int t = 0; t < kT; ++t) s += bf2f(cs[t * kT + tid]) * kern[t];
    lgv = s * 40.0f;
  }
  softmax196(lgv, tid, red, attnQ + (size_t)b * kT);
}

// ---------------------------------------------------------------------------
// Kernel 3: out = feat * (1 + attn[b, t]), float4 both sides.
// First half of out = class, second half = query. 196 floats = 49 float4/row.
// ---------------------------------------------------------------------------
__global__ __launch_bounds__(256) void scale_kernel(
    const float4* __restrict__ cf, const float4* __restrict__ qf,
    const float* __restrict__ attnC, const float* __restrict__ attnQ,
    float4* __restrict__ out)
{
  constexpr unsigned NC4 = (unsigned)kB * kC * 49u;  // 16,056,320
  const unsigned i = blockIdx.x * 256u + threadIdx.x; // grid sized exactly 2*NC4
  unsigned j;
  const float4* fp;
  const float* ap;
  if (i < NC4) { j = i;       fp = cf; ap = attnC; }
  else         { j = i - NC4; fp = qf; ap = attnQ; }
  const unsigned col = j % 49u;
  const unsigned bc  = j / 49u;
  const unsigned b   = bc / (unsigned)kC;
  const float4 f = fp[j];
  const float4 a = *(const float4*)(ap + (size_t)b * kT + col * 4u);
  float4 r;
  r.x = f.x * (1.f + a.x);
  r.y = f.y * (1.f + a.y);
  r.z = f.z * (1.f + a.z);
  r.w = f.w * (1.f + a.w);
  out[i] = r;
}

extern "C" void kernel_launch(void* const* d_in, const int* in_sizes, int n_in,
                              void* d_out, int out_size, void* d_ws, size_t ws_size,
                              hipStream_t stream) {
  const float* cf  = (const float*)d_in[0];
  const float* qf  = (const float*)d_in[1];
  const float* cw1 = (const float*)d_in[2];
  const float* cb1 = (const float*)d_in[3];
  const float* cw2 = (const float*)d_in[4];
  const float* cb2 = (const float*)d_in[5];
  const float* qw1 = (const float*)d_in[6];
  const float* qb1 = (const float*)d_in[7];
  const float* qw2 = (const float*)d_in[8];
  const float* qb2 = (const float*)d_in[9];
  float* out = (float*)d_out;

  // workspace layout
  char* ws = (char*)d_ws;
  unsigned short* corr = (unsigned short*)ws;                       // 512*196*196*2 = 39,337,984 B
  float* attn_c = (float*)(ws + (size_t)kB * kT * kT * 2);          // 512*196*4
  float* attn_q = attn_c + (size_t)kB * kT;

  corr_kernel<<<kB, 448, 0, stream>>>(cf, qf, corr);
  attn_kernel<<<kB, 256, 0, stream>>>(corr, cw1, cb1, cw2, cb2,
                                      qw1, qb1, qw2, qb2, attn_c, attn_q);
  constexpr unsigned total4 = 2u * (unsigned)kB * kC * 49u;  // 32,112,640
  scale_kernel<<<total4 / 256u, 256, 0, stream>>>(
      (const float4*)cf, (const float4*)qf, attn_c, attn_q, (float4*)out);
}